// Round 3
// baseline (1037.936 us; speedup 1.0000x reference)
//
#include <hip/hip_runtime.h>

#define HW_T 1024
#define HW_S 4096

// ---------------------------------------------------------------------------
// Kernel 1: fused Q & K 1x1 conv.  Q[b][cq][hw] = sum_c qw[cq][c]*rgb[c][hw]+qb
// 2 hw positions per thread (float2): each broadcast weight read feeds 4 FMAs.
// grid (8, 64): y -> (branch, batch); x*512 -> hw chunk (t exits x>=2).
// ---------------------------------------------------------------------------
__global__ __launch_bounds__(256)
void qk_kernel(const float* __restrict__ rgb_t, const float* __restrict__ rgb_s,
               const float* __restrict__ qw_t, const float* __restrict__ kw_t,
               const float* __restrict__ qw_s, const float* __restrict__ kw_s,
               const float* __restrict__ qb_t, const float* __restrict__ kb_t,
               const float* __restrict__ qb_s, const float* __restrict__ kb_s,
               float* __restrict__ Q_t, float* __restrict__ K_t,
               float* __restrict__ Q_s, float* __restrict__ K_s) {
    const int zb = blockIdx.y, br = zb >> 5, b = zb & 31;
    const int HW = br ? HW_S : HW_T;
    if ((int)blockIdx.x * 512 >= HW) return;   // whole-block uniform exit

    __shared__ float2 sWK[256 * 32];           // [c][cq] -> {qw, kw}, 64 KiB
    const float* qw = br ? qw_s : qw_t;
    const float* kw = br ? kw_s : kw_t;
    const int tid = threadIdx.x;
    for (int idx = tid; idx < 8192; idx += 256) {
        const int cq = idx >> 8, c = idx & 255;          // idx = cq*256 + c
        sWK[(c << 5) + cq] = make_float2(qw[idx], kw[idx]);
    }

    const float* qb = br ? qb_s : qb_t;
    const float* kb = br ? kb_s : kb_t;
    float2 qacc[32], kacc[32];
#pragma unroll
    for (int cq = 0; cq < 32; cq++) {
        qacc[cq] = make_float2(qb[cq], qb[cq]);
        kacc[cq] = make_float2(kb[cq], kb[cq]);
    }
    __syncthreads();

    const int hw = blockIdx.x * 512 + tid * 2;
    const float* rgb = (br ? rgb_s : rgb_t) + (size_t)b * 256 * HW + hw;
#pragma unroll 2
    for (int c = 0; c < 256; c++) {
        const float2 r = *(const float2*)&rgb[(size_t)c * HW];
        const float2* wrow = &sWK[c << 5];
#pragma unroll
        for (int cq = 0; cq < 32; cq++) {
            const float2 w = wrow[cq];
            qacc[cq].x = fmaf(r.x, w.x, qacc[cq].x);
            qacc[cq].y = fmaf(r.y, w.x, qacc[cq].y);
            kacc[cq].x = fmaf(r.x, w.y, kacc[cq].x);
            kacc[cq].y = fmaf(r.y, w.y, kacc[cq].y);
        }
    }
    float* Q = (br ? Q_s : Q_t) + (size_t)b * 32 * HW + hw;
    float* K = (br ? K_s : K_t) + (size_t)b * 32 * HW + hw;
#pragma unroll
    for (int cq = 0; cq < 32; cq++) {
        *(float2*)&Q[(size_t)cq * HW] = qacc[cq];
        *(float2*)&K[(size_t)cq * HW] = kacc[cq];
    }
}

// ---------------------------------------------------------------------------
// Kernel 2: energy (Qr @ Kr^T over M) + reversed-softmax -> attn (fp32)
// (unchanged this round)
// ---------------------------------------------------------------------------
__global__ __launch_bounds__(256)
void attn_kernel(const float* __restrict__ Q_t, const float* __restrict__ K_t,
                 const float* __restrict__ Q_s, const float* __restrict__ K_s,
                 float* __restrict__ A_t, float* __restrict__ A_s) {
    const int zb = blockIdx.y, br = zb >> 5, b = zb & 31;
    const int M = br ? (HW_S / 8) : (HW_T / 8);          // 512 / 128
    const float* Qb = (br ? Q_s : Q_t) + (size_t)b * 32 * (br ? HW_S : HW_T);
    const float* Kb = (br ? K_s : K_t) + (size_t)b * 32 * (br ? HW_S : HW_T);
    float* attn = (br ? A_s : A_t) + (size_t)b * 65536;
    const int c0 = blockIdx.x * 32;

    __shared__ float sK[256][33];
    __shared__ float sQ[32][33];
    __shared__ float eT[32][260];

    const int tid = threadIdx.x;
    const int dx = tid & 31, cy = tid >> 5;   // thread covers c = cy*4+i, d = dx+32j
    float acc[4][8] = {};

    for (int m0 = 0; m0 < M; m0 += 32) {
        __syncthreads();
        {
            const int rr = tid >> 3;
            const int cc = (tid & 7) << 2;
#pragma unroll
            for (int p = 0; p < 8; p++) {
                const int row = (p << 5) + rr;
                const float4 v = *(const float4*)(Kb + (size_t)row * M + m0 + cc);
                sK[row][cc] = v.x; sK[row][cc + 1] = v.y;
                sK[row][cc + 2] = v.z; sK[row][cc + 3] = v.w;
            }
            const float4 qv = *(const float4*)(Qb + (size_t)(c0 + rr) * M + m0 + cc);
            sQ[rr][cc] = qv.x; sQ[rr][cc + 1] = qv.y;
            sQ[rr][cc + 2] = qv.z; sQ[rr][cc + 3] = qv.w;
        }
        __syncthreads();
#pragma unroll 2
        for (int m = 0; m < 32; m++) {
            float kv[8];
#pragma unroll
            for (int j = 0; j < 8; j++) kv[j] = sK[dx + (j << 5)][m];
#pragma unroll
            for (int i = 0; i < 4; i++) {
                const float qv = sQ[(cy << 2) + i][m];
#pragma unroll
                for (int j = 0; j < 8; j++) acc[i][j] = fmaf(qv, kv[j], acc[i][j]);
            }
        }
    }

#pragma unroll
    for (int i = 0; i < 4; i++)
#pragma unroll
        for (int j = 0; j < 8; j++)
            eT[(cy << 2) + i][dx + (j << 5)] = acc[i][j];
    __syncthreads();

    // softmax: 8 threads per row (consecutive lanes), 32 cols each (stride 8)
    const int r = tid >> 3, s8 = tid & 7;
    float p[32];
    float mn = 3.0e38f;
#pragma unroll
    for (int m = 0; m < 32; m++) { p[m] = eT[r][s8 + (m << 3)]; mn = fminf(mn, p[m]); }
    mn = fminf(mn, __shfl_xor(mn, 1));
    mn = fminf(mn, __shfl_xor(mn, 2));
    mn = fminf(mn, __shfl_xor(mn, 4));
    float sum = 0.f;
#pragma unroll
    for (int m = 0; m < 32; m++) { p[m] = __expf(mn - p[m]); sum += p[m]; }
    sum += __shfl_xor(sum, 1);
    sum += __shfl_xor(sum, 2);
    sum += __shfl_xor(sum, 4);
    const float rinv = 1.0f / sum;
#pragma unroll
    for (int m = 0; m < 32; m++) eT[r][s8 + (m << 3)] = p[m] * rinv;
    __syncthreads();

    for (int idx = tid; idx < 2048; idx += 256) {
        const int row = idx >> 6, c4 = (idx & 63) << 2;
        const float4 v = *(const float4*)&eT[row][c4];
        *(float4*)(attn + (size_t)(c0 + row) * 256 + c4) = v;
    }
}

// ---------------------------------------------------------------------------
// Kernel 3/5: tiled GEMM  C[c][n] = sum_k A[c][k] * B[k][n]
//   128x128 tile, 256 threads, 8x8 micro-tile (SPLIT rows/cols for
//   conflict-free ds_read_b128), K-step 32, reg prefetch.
//   amdgpu_waves_per_eu(2,2): register BUDGET = 512/2 = 256 VGPR.
//   (__launch_bounds__(256,2) only set the MIN waves -> allocator still
//   targeted 8 waves/EU = 64 VGPR and spilled acc; max=2 is the real knob.)
//   FINAL=0: store fp32 W' tile.  FINAL=1: out = alpha*(acc + b'[c]) + z.
// grid (ceil(N/128), 2, 64).
// ---------------------------------------------------------------------------
#define ROW_FMA(I, AV)                                        \
    acc[I][0] = fmaf(AV, b0.x, acc[I][0]);                    \
    acc[I][1] = fmaf(AV, b0.y, acc[I][1]);                    \
    acc[I][2] = fmaf(AV, b0.z, acc[I][2]);                    \
    acc[I][3] = fmaf(AV, b0.w, acc[I][3]);                    \
    acc[I][4] = fmaf(AV, b1.x, acc[I][4]);                    \
    acc[I][5] = fmaf(AV, b1.y, acc[I][5]);                    \
    acc[I][6] = fmaf(AV, b1.z, acc[I][6]);                    \
    acc[I][7] = fmaf(AV, b1.w, acc[I][7]);

template <int FINAL>
__global__ __launch_bounds__(256)
__attribute__((amdgpu_waves_per_eu(2, 2)))
void gemm128(const float* __restrict__ A_t, const float* __restrict__ A_s,
             const float* __restrict__ B_t, const float* __restrict__ B_s,
             float* __restrict__ C_t, float* __restrict__ C_s,
             float* __restrict__ O_t, float* __restrict__ O_s,
             const float* __restrict__ bp_t, const float* __restrict__ bp_s,
             const float* __restrict__ alpha_p, const float* __restrict__ beta_p,
             int N_t, int N_s) {
    const int zb = blockIdx.z, br = zb >> 5, b = zb & 31;
    const int N = br ? N_s : N_t;
    const int n0 = blockIdx.x * 128;
    if (n0 >= N) return;                        // whole-block uniform exit
    const int c0 = blockIdx.y * 128;
    const float* A = (br ? A_s : A_t) + (size_t)b * 65536;
    const float* Bm = (br ? B_s : B_t);
    if (FINAL) Bm += (size_t)b * 256 * (size_t)N;

    // k-major LDS tiles; 132-float row stride keeps float4 alignment (528B)
    __shared__ float sA[32][132];
    __shared__ float sB[32][132];

    const int tid = threadIdx.x;
    const int tx = tid & 15, ty = tid >> 4;     // micro-tile coords

    // staging maps (coalesced 128B row chunks):
    // A: 8 lanes/row, float4 along k.  c-row = ar+32p, k = aslot*4..+3
    const int ar = tid >> 3, aslot = tid & 7;
    // B: 32 lanes/row, float4 along n.  k-row = brow+8p, n = bcol*4..+3
    const int brow = tid >> 5, bcol = tid & 31;

    const float* Abase = A + (size_t)(c0 + ar) * 256 + aslot * 4;
    const float* Bbase = Bm + (size_t)brow * N + n0 + bcol * 4;

    float acc[8][8] = {};
    float4 pa[4], pb[4];

    // prefetch tile k0 = 0 into registers
#pragma unroll
    for (int p = 0; p < 4; p++)
        pa[p] = *(const float4*)(Abase + (size_t)(32 * p) * 256);
#pragma unroll
    for (int p = 0; p < 4; p++)
        pb[p] = *(const float4*)(Bbase + (size_t)(8 * p) * N);

    for (int k0 = 0; k0 < 256; k0 += 32) {
        __syncthreads();                        // LDS free to overwrite
        {   // A scatter-transpose -> sA[k][c]
#pragma unroll
            for (int p = 0; p < 4; p++) {
                sA[aslot * 4 + 0][ar + 32 * p] = pa[p].x;
                sA[aslot * 4 + 1][ar + 32 * p] = pa[p].y;
                sA[aslot * 4 + 2][ar + 32 * p] = pa[p].z;
                sA[aslot * 4 + 3][ar + 32 * p] = pa[p].w;
            }
        }
        {   // B direct -> sB[k][n]
#pragma unroll
            for (int p = 0; p < 4; p++)
                *(float4*)&sB[brow + 8 * p][bcol * 4] = pb[p];
        }
        __syncthreads();

        if (k0 + 32 < 256) {                    // prefetch next tile under compute
            const int kn = k0 + 32;
#pragma unroll
            for (int p = 0; p < 4; p++)
                pa[p] = *(const float4*)(Abase + (size_t)(32 * p) * 256 + kn);
#pragma unroll
            for (int p = 0; p < 4; p++)
                pb[p] = *(const float4*)(Bbase + (size_t)(kn + 8 * p) * N);
        }

#pragma unroll 4
        for (int k = 0; k < 32; k++) {
            const float4 a0 = *(const float4*)&sA[k][ty * 4];
            const float4 a1 = *(const float4*)&sA[k][64 + ty * 4];
            const float4 b0 = *(const float4*)&sB[k][tx * 4];
            const float4 b1 = *(const float4*)&sB[k][64 + tx * 4];
            ROW_FMA(0, a0.x)
            ROW_FMA(1, a0.y)
            ROW_FMA(2, a0.z)
            ROW_FMA(3, a0.w)
            ROW_FMA(4, a1.x)
            ROW_FMA(5, a1.y)
            ROW_FMA(6, a1.z)
            ROW_FMA(7, a1.w)
        }
    }

    if (FINAL) {
        const float alpha = br ? beta_p[0] : alpha_p[0];
        const float* bp = (br ? bp_s : bp_t) + b * 256;
        float* O = (br ? O_s : O_t) + (size_t)b * 256 * (size_t)N;
#pragma unroll
        for (int h = 0; h < 2; h++) {
#pragma unroll
            for (int i = 0; i < 4; i++) {
                const int ii = h * 4 + i;
                const int c = c0 + h * 64 + ty * 4 + i;
                const float bpv = bp[c];
                const size_t off0 = (size_t)c * N + n0 + tx * 4;
                const size_t off1 = off0 + 64;
                const float4 z0 = *(const float4*)(Bm + off0);   // Bm IS z
                const float4 z1 = *(const float4*)(Bm + off1);
                float4 o0, o1;
                o0.x = fmaf(alpha, acc[ii][0] + bpv, z0.x);
                o0.y = fmaf(alpha, acc[ii][1] + bpv, z0.y);
                o0.z = fmaf(alpha, acc[ii][2] + bpv, z0.z);
                o0.w = fmaf(alpha, acc[ii][3] + bpv, z0.w);
                o1.x = fmaf(alpha, acc[ii][4] + bpv, z1.x);
                o1.y = fmaf(alpha, acc[ii][5] + bpv, z1.y);
                o1.z = fmaf(alpha, acc[ii][6] + bpv, z1.z);
                o1.w = fmaf(alpha, acc[ii][7] + bpv, z1.w);
                *(float4*)(O + off0) = o0;
                *(float4*)(O + off1) = o1;
            }
        }
    } else {
        float* Co = (br ? C_s : C_t) + (size_t)b * 65536;
#pragma unroll
        for (int h = 0; h < 2; h++) {
#pragma unroll
            for (int i = 0; i < 4; i++) {
                const int ii = h * 4 + i;
                const int c = c0 + h * 64 + ty * 4 + i;
                const size_t off0 = (size_t)c * 256 + n0 + tx * 4;
                *(float4*)(Co + off0) =
                    make_float4(acc[ii][0], acc[ii][1], acc[ii][2], acc[ii][3]);
                *(float4*)(Co + off0 + 64) =
                    make_float4(acc[ii][4], acc[ii][5], acc[ii][6], acc[ii][7]);
            }
        }
    }
}

// ---------------------------------------------------------------------------
// Kernel 4: b'[b][c] = sum_d attn[b][c][d] * vb[d]   (GEMV; vb is tiny)
// ---------------------------------------------------------------------------
__global__ __launch_bounds__(256)
void bprime_kernel(const float* __restrict__ A_t, const float* __restrict__ A_s,
                   const float* __restrict__ vb_t, const float* __restrict__ vb_s,
                   float* __restrict__ bp_t, float* __restrict__ bp_s) {
    const int bx = blockIdx.x, br = bx >> 5, b = bx & 31;
    const float* A = (br ? A_s : A_t) + (size_t)b * 65536;
    const float* vb = br ? vb_s : vb_t;
    float* bp = (br ? bp_s : bp_t) + b * 256;
    __shared__ float svb[256];
    svb[threadIdx.x] = vb[threadIdx.x];
    __syncthreads();
    const int wave = threadIdx.x >> 6, lane = threadIdx.x & 63;
    for (int c = wave; c < 256; c += 4) {
        const float4 a = *(const float4*)(A + (size_t)c * 256 + (lane << 2));
        const int l4 = lane << 2;
        float s = a.x * svb[l4] + a.y * svb[l4 + 1] + a.z * svb[l4 + 2] + a.w * svb[l4 + 3];
#pragma unroll
        for (int off = 32; off > 0; off >>= 1) s += __shfl_down(s, off);
        if (lane == 0) bp[c] = s;
    }
}

// ---------------------------------------------------------------------------
extern "C" void kernel_launch(void* const* d_in, const int* in_sizes, int n_in,
                              void* d_out, int out_size, void* d_ws, size_t ws_size,
                              hipStream_t stream) {
    const float* rgb_t = (const float*)d_in[0];
    const float* rgb_s = (const float*)d_in[1];
    const float* z_t   = (const float*)d_in[2];
    const float* z_s   = (const float*)d_in[3];
    const float* tq_w  = (const float*)d_in[4];
    const float* tq_b  = (const float*)d_in[5];
    const float* tk_w  = (const float*)d_in[6];
    const float* tk_b  = (const float*)d_in[7];
    const float* tv_w  = (const float*)d_in[8];
    const float* tv_b  = (const float*)d_in[9];
    const float* sq_w  = (const float*)d_in[10];
    const float* sq_b  = (const float*)d_in[11];
    const float* sk_w  = (const float*)d_in[12];
    const float* sk_b  = (const float*)d_in[13];
    const float* sv_w  = (const float*)d_in[14];
    const float* sv_b  = (const float*)d_in[15];
    const float* alpha = (const float*)d_in[16];
    const float* beta  = (const float*)d_in[17];

    // workspace layout (fp32).  W' aliases the Q/K region (attn is the last
    // reader of Q/K; gemm128<0> runs after attn_kernel).  Total ~58.8 MB.
    float* ws  = (float*)d_ws;
    float* At  = ws;                       // 32*256*256   attn (t)
    float* As_ = At + 2097152;             // attn (s)
    float* bt  = As_ + 2097152;            // 32*256 b' (t)
    float* bs  = bt + 8192;                // b' (s)
    float* Qt  = bs + 8192;                // 32*32*1024
    float* Kt  = Qt + 1048576;
    float* Qs  = Kt + 1048576;             // 32*32*4096
    float* Ks  = Qs + 4194304;
    float* Wt  = Qt;                       // alias: W' (t) over Qt/Kt
    float* Ws_ = Qs;                       // alias: W' (s) over Qs

    float* out_t = (float*)d_out;
    float* out_s = out_t + (size_t)32 * 256 * HW_T;   // 8,388,608 elements

    qk_kernel<<<dim3(8, 64), 256, 0, stream>>>(
        rgb_t, rgb_s, tq_w, tk_w, sq_w, sk_w,
        tq_b, tk_b, sq_b, sk_b, Qt, Kt, Qs, Ks);

    attn_kernel<<<dim3(8, 64), 256, 0, stream>>>(Qt, Kt, Qs, Ks, At, As_);

    bprime_kernel<<<dim3(64), 256, 0, stream>>>(At, As_, tv_b, sv_b, bt, bs);

    gemm128<0><<<dim3(2, 2, 64), 256, 0, stream>>>(
        At, As_, tv_w, sv_w, Wt, Ws_,
        (float*)nullptr, (float*)nullptr, (const float*)nullptr, (const float*)nullptr,
        (const float*)nullptr, (const float*)nullptr, 256, 256);

    gemm128<1><<<dim3(32, 2, 64), 256, 0, stream>>>(
        Wt, Ws_, z_t, z_s, (float*)nullptr, (float*)nullptr,
        out_t, out_s, bt, bs, alpha, beta, HW_T, HW_S);
}

// Round 4
// 965.352 us; speedup vs baseline: 1.0752x; 1.0752x over previous
//
#include <hip/hip_runtime.h>

#define HW_T 1024
#define HW_S 4096

// ---------------------------------------------------------------------------
// Kernel 1: fused Q & K 1x1 conv.  Q[b][cq][hw] = sum_c qw[cq][c]*rgb[c][hw]+qb
// 2 hw positions per thread (float2); weights read as float4 (2 cq per
// ds_read_b128) -> 16 LDS instrs per channel instead of 32.
// grid (8, 64): y -> (branch, batch); x*512 -> hw chunk (t exits x>=2).
// ---------------------------------------------------------------------------
__global__ __launch_bounds__(256)
void qk_kernel(const float* __restrict__ rgb_t, const float* __restrict__ rgb_s,
               const float* __restrict__ qw_t, const float* __restrict__ kw_t,
               const float* __restrict__ qw_s, const float* __restrict__ kw_s,
               const float* __restrict__ qb_t, const float* __restrict__ kb_t,
               const float* __restrict__ qb_s, const float* __restrict__ kb_s,
               float* __restrict__ Q_t, float* __restrict__ K_t,
               float* __restrict__ Q_s, float* __restrict__ K_s) {
    const int zb = blockIdx.y, br = zb >> 5, b = zb & 31;
    const int HW = br ? HW_S : HW_T;
    if ((int)blockIdx.x * 512 >= HW) return;   // whole-block uniform exit

    __shared__ float2 sWK[256 * 32];           // [c][cq] -> {qw, kw}, 64 KiB
    const float* qw = br ? qw_s : qw_t;
    const float* kw = br ? kw_s : kw_t;
    const int tid = threadIdx.x;
    for (int idx = tid; idx < 8192; idx += 256) {
        const int cq = idx >> 8, c = idx & 255;          // idx = cq*256 + c
        sWK[(c << 5) + cq] = make_float2(qw[idx], kw[idx]);
    }

    const float* qb = br ? qb_s : qb_t;
    const float* kb = br ? kb_s : kb_t;
    float2 qacc[32], kacc[32];
#pragma unroll
    for (int cq = 0; cq < 32; cq++) {
        qacc[cq] = make_float2(qb[cq], qb[cq]);
        kacc[cq] = make_float2(kb[cq], kb[cq]);
    }
    __syncthreads();

    const int hw = blockIdx.x * 512 + tid * 2;
    const float* rgb = (br ? rgb_s : rgb_t) + (size_t)b * 256 * HW + hw;
#pragma unroll 2
    for (int c = 0; c < 256; c++) {
        const float2 r = *(const float2*)&rgb[(size_t)c * HW];
        const float4* wrow = (const float4*)&sWK[c << 5];   // 16 x {qw0,kw0,qw1,kw1}
#pragma unroll
        for (int cq2 = 0; cq2 < 16; cq2++) {
            const float4 w = wrow[cq2];
            const int cq = cq2 * 2;
            qacc[cq].x     = fmaf(r.x, w.x, qacc[cq].x);
            qacc[cq].y     = fmaf(r.y, w.x, qacc[cq].y);
            kacc[cq].x     = fmaf(r.x, w.y, kacc[cq].x);
            kacc[cq].y     = fmaf(r.y, w.y, kacc[cq].y);
            qacc[cq + 1].x = fmaf(r.x, w.z, qacc[cq + 1].x);
            qacc[cq + 1].y = fmaf(r.y, w.z, qacc[cq + 1].y);
            kacc[cq + 1].x = fmaf(r.x, w.w, kacc[cq + 1].x);
            kacc[cq + 1].y = fmaf(r.y, w.w, kacc[cq + 1].y);
        }
    }
    float* Q = (br ? Q_s : Q_t) + (size_t)b * 32 * HW + hw;
    float* K = (br ? K_s : K_t) + (size_t)b * 32 * HW + hw;
#pragma unroll
    for (int cq = 0; cq < 32; cq++) {
        *(float2*)&Q[(size_t)cq * HW] = qacc[cq];
        *(float2*)&K[(size_t)cq * HW] = kacc[cq];
    }
}

// ---------------------------------------------------------------------------
// Kernel 2: energy (Qr @ Kr^T over M) + reversed-softmax -> attn (fp32)
// (unchanged this round)
// ---------------------------------------------------------------------------
__global__ __launch_bounds__(256)
void attn_kernel(const float* __restrict__ Q_t, const float* __restrict__ K_t,
                 const float* __restrict__ Q_s, const float* __restrict__ K_s,
                 float* __restrict__ A_t, float* __restrict__ A_s) {
    const int zb = blockIdx.y, br = zb >> 5, b = zb & 31;
    const int M = br ? (HW_S / 8) : (HW_T / 8);          // 512 / 128
    const float* Qb = (br ? Q_s : Q_t) + (size_t)b * 32 * (br ? HW_S : HW_T);
    const float* Kb = (br ? K_s : K_t) + (size_t)b * 32 * (br ? HW_S : HW_T);
    float* attn = (br ? A_s : A_t) + (size_t)b * 65536;
    const int c0 = blockIdx.x * 32;

    __shared__ float sK[256][33];
    __shared__ float sQ[32][33];
    __shared__ float eT[32][260];

    const int tid = threadIdx.x;
    const int dx = tid & 31, cy = tid >> 5;   // thread covers c = cy*4+i, d = dx+32j
    float acc[4][8] = {};

    for (int m0 = 0; m0 < M; m0 += 32) {
        __syncthreads();
        {
            const int rr = tid >> 3;
            const int cc = (tid & 7) << 2;
#pragma unroll
            for (int p = 0; p < 8; p++) {
                const int row = (p << 5) + rr;
                const float4 v = *(const float4*)(Kb + (size_t)row * M + m0 + cc);
                sK[row][cc] = v.x; sK[row][cc + 1] = v.y;
                sK[row][cc + 2] = v.z; sK[row][cc + 3] = v.w;
            }
            const float4 qv = *(const float4*)(Qb + (size_t)(c0 + rr) * M + m0 + cc);
            sQ[rr][cc] = qv.x; sQ[rr][cc + 1] = qv.y;
            sQ[rr][cc + 2] = qv.z; sQ[rr][cc + 3] = qv.w;
        }
        __syncthreads();
#pragma unroll 2
        for (int m = 0; m < 32; m++) {
            float kv[8];
#pragma unroll
            for (int j = 0; j < 8; j++) kv[j] = sK[dx + (j << 5)][m];
#pragma unroll
            for (int i = 0; i < 4; i++) {
                const float qv = sQ[(cy << 2) + i][m];
#pragma unroll
                for (int j = 0; j < 8; j++) acc[i][j] = fmaf(qv, kv[j], acc[i][j]);
            }
        }
    }

#pragma unroll
    for (int i = 0; i < 4; i++)
#pragma unroll
        for (int j = 0; j < 8; j++)
            eT[(cy << 2) + i][dx + (j << 5)] = acc[i][j];
    __syncthreads();

    // softmax: 8 threads per row (consecutive lanes), 32 cols each (stride 8)
    const int r = tid >> 3, s8 = tid & 7;
    float p[32];
    float mn = 3.0e38f;
#pragma unroll
    for (int m = 0; m < 32; m++) { p[m] = eT[r][s8 + (m << 3)]; mn = fminf(mn, p[m]); }
    mn = fminf(mn, __shfl_xor(mn, 1));
    mn = fminf(mn, __shfl_xor(mn, 2));
    mn = fminf(mn, __shfl_xor(mn, 4));
    float sum = 0.f;
#pragma unroll
    for (int m = 0; m < 32; m++) { p[m] = __expf(mn - p[m]); sum += p[m]; }
    sum += __shfl_xor(sum, 1);
    sum += __shfl_xor(sum, 2);
    sum += __shfl_xor(sum, 4);
    const float rinv = 1.0f / sum;
#pragma unroll
    for (int m = 0; m < 32; m++) eT[r][s8 + (m << 3)] = p[m] * rinv;
    __syncthreads();

    for (int idx = tid; idx < 2048; idx += 256) {
        const int row = idx >> 6, c4 = (idx & 63) << 2;
        const float4 v = *(const float4*)&eT[row][c4];
        *(float4*)(attn + (size_t)(c0 + row) * 256 + c4) = v;
    }
}

// ---------------------------------------------------------------------------
// Kernel 3/5: tiled GEMM  C[c][n] = sum_k A[c][k] * B[k][n]
//   128x128 tile, 256 threads, 8x8 SPLIT micro-tile, K-step 32.
//   FULLY SCALARIZED: no per-thread arrays anywhere (r3 evidence: pa[]/pb[]
//   failed SROA -> alloca -> scratch spill (r1/r2 WRITE_SIZE) or LDS
//   promotion (r3 LDS 50176).  Named float4 regs make SROA trivial.
//   Plain __launch_bounds__(256): ~120-reg working set -> 4 waves/EU tier.
//   FINAL=0: store fp32 W' tile.  FINAL=1: out = alpha*(acc + b'[c]) + z.
// grid (ceil(N/128), 2, 64).
// ---------------------------------------------------------------------------
#define FR(AL, AR, AV)                                        \
    AL.x = fmaf(AV, b0.x, AL.x); AL.y = fmaf(AV, b0.y, AL.y); \
    AL.z = fmaf(AV, b0.z, AL.z); AL.w = fmaf(AV, b0.w, AL.w); \
    AR.x = fmaf(AV, b1.x, AR.x); AR.y = fmaf(AV, b1.y, AR.y); \
    AR.z = fmaf(AV, b1.z, AR.z); AR.w = fmaf(AV, b1.w, AR.w);

#define STA(P, OFF)                                           \
    sAf[(aslot * 4 + 0) * 132 + ar + (OFF)] = P.x;            \
    sAf[(aslot * 4 + 1) * 132 + ar + (OFF)] = P.y;            \
    sAf[(aslot * 4 + 2) * 132 + ar + (OFF)] = P.z;            \
    sAf[(aslot * 4 + 3) * 132 + ar + (OFF)] = P.w;

#define EPI_FIN(AL, AR, CROW) {                               \
    const int c = (CROW);                                     \
    const float bpv = bp[c];                                  \
    const size_t off0 = (size_t)c * N + n0 + (tx << 2);       \
    const float4 z0 = *(const float4*)(Bm + off0);            \
    const float4 z1 = *(const float4*)(Bm + off0 + 64);       \
    float4 o0, o1;                                            \
    o0.x = fmaf(alpha, AL.x + bpv, z0.x);                     \
    o0.y = fmaf(alpha, AL.y + bpv, z0.y);                     \
    o0.z = fmaf(alpha, AL.z + bpv, z0.z);                     \
    o0.w = fmaf(alpha, AL.w + bpv, z0.w);                     \
    o1.x = fmaf(alpha, AR.x + bpv, z1.x);                     \
    o1.y = fmaf(alpha, AR.y + bpv, z1.y);                     \
    o1.z = fmaf(alpha, AR.z + bpv, z1.z);                     \
    o1.w = fmaf(alpha, AR.w + bpv, z1.w);                     \
    *(float4*)(O + off0) = o0;                                \
    *(float4*)(O + off0 + 64) = o1; }

#define EPI_STO(AL, AR, CROW) {                               \
    const int c = (CROW);                                     \
    const size_t off0 = (size_t)c * 256 + n0 + (tx << 2);     \
    *(float4*)(Co + off0) = AL;                               \
    *(float4*)(Co + off0 + 64) = AR; }

template <int FINAL>
__global__ __launch_bounds__(256)
void gemm128(const float* __restrict__ A_t, const float* __restrict__ A_s,
             const float* __restrict__ B_t, const float* __restrict__ B_s,
             float* __restrict__ C_t, float* __restrict__ C_s,
             float* __restrict__ O_t, float* __restrict__ O_s,
             const float* __restrict__ bp_t, const float* __restrict__ bp_s,
             const float* __restrict__ alpha_p, const float* __restrict__ beta_p,
             int N_t, int N_s) {
    const int zb = blockIdx.z, br = zb >> 5, b = zb & 31;
    const int N = br ? N_s : N_t;
    const int n0 = blockIdx.x * 128;
    if (n0 >= N) return;                        // whole-block uniform exit
    const int c0 = blockIdx.y * 128;
    const float* A = (br ? A_s : A_t) + (size_t)b * 65536;
    const float* Bm = (br ? B_s : B_t);
    if (FINAL) Bm += (size_t)b * 256 * (size_t)N;

    // k-major LDS tiles; 33-float4 row stride (528 B) keeps alignment
    __shared__ float4 sA4[32][33];
    __shared__ float4 sB4[32][33];
    float* sAf = (float*)sA4;                   // row stride 132 floats

    const int tid = threadIdx.x;
    const int tx = tid & 15, ty = tid >> 4;     // micro-tile coords

    // staging maps (coalesced 128B row chunks):
    const int ar = tid >> 3, aslot = tid & 7;   // A: c-row ar+32p, k = aslot*4..
    const int brow = tid >> 5, bcol = tid & 31; // B: k-row brow+8p, n = bcol*4..

    const float* Abase = A + (size_t)(c0 + ar) * 256 + aslot * 4;
    const float* Bbase = Bm + (size_t)brow * N + n0 + bcol * 4;

    float4 aL0{}, aL1{}, aL2{}, aL3{}, aL4{}, aL5{}, aL6{}, aL7{};
    float4 aR0{}, aR1{}, aR2{}, aR3{}, aR4{}, aR5{}, aR6{}, aR7{};
    float4 pa0, pa1, pa2, pa3, pb0, pb1, pb2, pb3;

    // prefetch tile k0 = 0 into registers
    pa0 = *(const float4*)(Abase);
    pa1 = *(const float4*)(Abase + 8192);       // 32*256
    pa2 = *(const float4*)(Abase + 16384);      // 64*256
    pa3 = *(const float4*)(Abase + 24576);      // 96*256
    pb0 = *(const float4*)(Bbase);
    pb1 = *(const float4*)(Bbase + (size_t)8 * N);
    pb2 = *(const float4*)(Bbase + (size_t)16 * N);
    pb3 = *(const float4*)(Bbase + (size_t)24 * N);

    for (int k0 = 0; k0 < 256; k0 += 32) {
        __syncthreads();                        // LDS free to overwrite
        // A scatter-transpose -> sA[k][c]
        STA(pa0, 0) STA(pa1, 32) STA(pa2, 64) STA(pa3, 96)
        // B direct -> sB[k][n]
        sB4[brow][bcol]      = pb0;
        sB4[brow + 8][bcol]  = pb1;
        sB4[brow + 16][bcol] = pb2;
        sB4[brow + 24][bcol] = pb3;
        __syncthreads();

        if (k0 + 32 < 256) {                    // prefetch next tile under compute
            const int kn = k0 + 32;
            pa0 = *(const float4*)(Abase + kn);
            pa1 = *(const float4*)(Abase + 8192 + kn);
            pa2 = *(const float4*)(Abase + 16384 + kn);
            pa3 = *(const float4*)(Abase + 24576 + kn);
            pb0 = *(const float4*)(Bbase + (size_t)kn * N);
            pb1 = *(const float4*)(Bbase + (size_t)(kn + 8) * N);
            pb2 = *(const float4*)(Bbase + (size_t)(kn + 16) * N);
            pb3 = *(const float4*)(Bbase + (size_t)(kn + 24) * N);
        }

#pragma unroll 8
        for (int k = 0; k < 32; k++) {
            const float4 a0 = sA4[k][ty];
            const float4 a1 = sA4[k][16 + ty];
            const float4 b0 = sB4[k][tx];
            const float4 b1 = sB4[k][16 + tx];
            FR(aL0, aR0, a0.x)
            FR(aL1, aR1, a0.y)
            FR(aL2, aR2, a0.z)
            FR(aL3, aR3, a0.w)
            FR(aL4, aR4, a1.x)
            FR(aL5, aR5, a1.y)
            FR(aL6, aR6, a1.z)
            FR(aL7, aR7, a1.w)
        }
    }

    if (FINAL) {
        const float alpha = br ? beta_p[0] : alpha_p[0];
        const float* bp = (br ? bp_s : bp_t) + b * 256;
        float* O = (br ? O_s : O_t) + (size_t)b * 256 * (size_t)N;
        EPI_FIN(aL0, aR0, c0 + ty * 4 + 0)
        EPI_FIN(aL1, aR1, c0 + ty * 4 + 1)
        EPI_FIN(aL2, aR2, c0 + ty * 4 + 2)
        EPI_FIN(aL3, aR3, c0 + ty * 4 + 3)
        EPI_FIN(aL4, aR4, c0 + 64 + ty * 4 + 0)
        EPI_FIN(aL5, aR5, c0 + 64 + ty * 4 + 1)
        EPI_FIN(aL6, aR6, c0 + 64 + ty * 4 + 2)
        EPI_FIN(aL7, aR7, c0 + 64 + ty * 4 + 3)
    } else {
        float* Co = (br ? C_s : C_t) + (size_t)b * 65536;
        EPI_STO(aL0, aR0, c0 + ty * 4 + 0)
        EPI_STO(aL1, aR1, c0 + ty * 4 + 1)
        EPI_STO(aL2, aR2, c0 + ty * 4 + 2)
        EPI_STO(aL3, aR3, c0 + ty * 4 + 3)
        EPI_STO(aL4, aR4, c0 + 64 + ty * 4 + 0)
        EPI_STO(aL5, aR5, c0 + 64 + ty * 4 + 1)
        EPI_STO(aL6, aR6, c0 + 64 + ty * 4 + 2)
        EPI_STO(aL7, aR7, c0 + 64 + ty * 4 + 3)
    }
}

// ---------------------------------------------------------------------------
// Kernel 4: b'[b][c] = sum_d attn[b][c][d] * vb[d]   (GEMV; vb is tiny)
// ---------------------------------------------------------------------------
__global__ __launch_bounds__(256)
void bprime_kernel(const float* __restrict__ A_t, const float* __restrict__ A_s,
                   const float* __restrict__ vb_t, const float* __restrict__ vb_s,
                   float* __restrict__ bp_t, float* __restrict__ bp_s) {
    const int bx = blockIdx.x, br = bx >> 5, b = bx & 31;
    const float* A = (br ? A_s : A_t) + (size_t)b * 65536;
    const float* vb = br ? vb_s : vb_t;
    float* bp = (br ? bp_s : bp_t) + b * 256;
    __shared__ float svb[256];
    svb[threadIdx.x] = vb[threadIdx.x];
    __syncthreads();
    const int wave = threadIdx.x >> 6, lane = threadIdx.x & 63;
    for (int c = wave; c < 256; c += 4) {
        const float4 a = *(const float4*)(A + (size_t)c * 256 + (lane << 2));
        const int l4 = lane << 2;
        float s = a.x * svb[l4] + a.y * svb[l4 + 1] + a.z * svb[l4 + 2] + a.w * svb[l4 + 3];
#pragma unroll
        for (int off = 32; off > 0; off >>= 1) s += __shfl_down(s, off);
        if (lane == 0) bp[c] = s;
    }
}

// ---------------------------------------------------------------------------
extern "C" void kernel_launch(void* const* d_in, const int* in_sizes, int n_in,
                              void* d_out, int out_size, void* d_ws, size_t ws_size,
                              hipStream_t stream) {
    const float* rgb_t = (const float*)d_in[0];
    const float* rgb_s = (const float*)d_in[1];
    const float* z_t   = (const float*)d_in[2];
    const float* z_s   = (const float*)d_in[3];
    const float* tq_w  = (const float*)d_in[4];
    const float* tq_b  = (const float*)d_in[5];
    const float* tk_w  = (const float*)d_in[6];
    const float* tk_b  = (const float*)d_in[7];
    const float* tv_w  = (const float*)d_in[8];
    const float* tv_b  = (const float*)d_in[9];
    const float* sq_w  = (const float*)d_in[10];
    const float* sq_b  = (const float*)d_in[11];
    const float* sk_w  = (const float*)d_in[12];
    const float* sk_b  = (const float*)d_in[13];
    const float* sv_w  = (const float*)d_in[14];
    const float* sv_b  = (const float*)d_in[15];
    const float* alpha = (const float*)d_in[16];
    const float* beta  = (const float*)d_in[17];

    // workspace layout (fp32).  W' aliases the Q/K region (attn is the last
    // reader of Q/K; gemm128<0> runs after attn_kernel).  Total ~58.8 MB.
    float* ws  = (float*)d_ws;
    float* At  = ws;                       // 32*256*256   attn (t)
    float* As_ = At + 2097152;             // attn (s)
    float* bt  = As_ + 2097152;            // 32*256 b' (t)
    float* bs  = bt + 8192;                // b' (s)
    float* Qt  = bs + 8192;                // 32*32*1024
    float* Kt  = Qt + 1048576;
    float* Qs  = Kt + 1048576;             // 32*32*4096
    float* Ks  = Qs + 4194304;
    float* Wt  = Qt;                       // alias: W' (t) over Qt/Kt
    float* Ws_ = Qs;                       // alias: W' (s) over Qs

    float* out_t = (float*)d_out;
    float* out_s = out_t + (size_t)32 * 256 * HW_T;   // 8,388,608 elements

    qk_kernel<<<dim3(8, 64), 256, 0, stream>>>(
        rgb_t, rgb_s, tq_w, tk_w, sq_w, sk_w,
        tq_b, tk_b, sq_b, sk_b, Qt, Kt, Qs, Ks);

    attn_kernel<<<dim3(8, 64), 256, 0, stream>>>(Qt, Kt, Qs, Ks, At, As_);

    bprime_kernel<<<dim3(64), 256, 0, stream>>>(At, As_, tv_b, sv_b, bt, bs);

    gemm128<0><<<dim3(2, 2, 64), 256, 0, stream>>>(
        At, As_, tv_w, sv_w, Wt, Ws_,
        (float*)nullptr, (float*)nullptr, (const float*)nullptr, (const float*)nullptr,
        (const float*)nullptr, (const float*)nullptr, 256, 256);

    gemm128<1><<<dim3(32, 2, 64), 256, 0, stream>>>(
        Wt, Ws_, z_t, z_s, (float*)nullptr, (float*)nullptr,
        out_t, out_s, bt, bs, alpha, beta, HW_T, HW_S);
}